// Round 3
// baseline (360.883 us; speedup 1.0000x reference)
//
#include <hip/hip_runtime.h>
#include <hip/hip_bf16.h>

#define Bb 2
#define Hh 48
#define Ww 48
#define C 256
#define NH 8
#define HD 32
#define L 2304          // 48*48
#define NROW (Bb*L)     // 4608

typedef short  bf16x8 __attribute__((ext_vector_type(8)));
typedef float  f32x4  __attribute__((ext_vector_type(4)));
typedef unsigned short u16x4 __attribute__((ext_vector_type(4)));

__device__ __forceinline__ unsigned short f2b(float f) {
    union { float f; unsigned int u; } v; v.f = f;
    unsigned int r = v.u + 0x7fff + ((v.u >> 16) & 1);   // RNE
    return (unsigned short)(r >> 16);
}

#define LSTR 40   // u16 stride of LDS tile rows (80 B: 16B-aligned, odd multiple of 16 -> <=2-way banks)

// ---------------------------------------------------------------------------
// K1: MFMA GEMM for QKV projection + bias + k-scale + RoPE + head permute.
//     Tile 128(M) x 64(N), K=256 in 8 chunks of 32. Grid 36 x 12.
//     nb>>2 selects weight (q,k,v); (nb&3)*64 is the column block.
// ---------------------------------------------------------------------------
__global__ __launch_bounds__(256) void gemm_qkv(
    const float* __restrict__ x,
    const float* __restrict__ wq, const float* __restrict__ bq,
    const float* __restrict__ wk, const float* __restrict__ bk,
    const float* __restrict__ wv, const float* __restrict__ bv,
    const float* __restrict__ sinp, const float* __restrict__ cosp,
    unsigned short* __restrict__ q_bf, unsigned short* __restrict__ k_bf,
    float* __restrict__ v_perm)
{
    __shared__ __align__(16) unsigned short As[128 * LSTR];  // 10240 B
    __shared__ __align__(16) unsigned short Bs[64 * LSTR];   //  5120 B

    const int tid  = threadIdx.x;
    const int wave = tid >> 6, lane = tid & 63;
    const int quad = lane >> 4, l15 = lane & 15;
    const int mb = blockIdx.x % 36, nb = blockIdx.x / 36;
    const int row0 = mb * 128;
    const int wsel = nb >> 2, n0 = (nb & 3) * 64;
    const float* W    = (wsel == 0) ? wq : (wsel == 1) ? wk : wv;
    const float* bias = (wsel == 0) ? bq : (wsel == 1) ? bk : bv;

    const int mw = (wave & 1) * 64, nw = (wave >> 1) * 32;

    f32x4 acc[4][2];
    #pragma unroll
    for (int t = 0; t < 4; ++t)
        #pragma unroll
        for (int u = 0; u < 2; ++u) acc[t][u] = (f32x4){0,0,0,0};

    for (int kc = 0; kc < 8; ++kc) {
        const int k0 = kc * 32;
        __syncthreads();
        // ---- stage A: 128x32 fp32 -> bf16 LDS. thread: row=tid>>1, half=tid&1
        {
            const int row = tid >> 1, h = tid & 1;
            const float* src = x + (size_t)(row0 + row) * C + k0 + h * 16;
            #pragma unroll
            for (int j = 0; j < 4; ++j) {
                const f32x4 v = *(const f32x4*)(src + j * 4);
                u16x4 p = { f2b(v[0]), f2b(v[1]), f2b(v[2]), f2b(v[3]) };
                *(u16x4*)&As[row * LSTR + h * 16 + j * 4] = p;
            }
        }
        // ---- stage B transposed: W[k0+k][n0+n] -> Bs[n][k]. thread: n=tid&63, kg=tid>>6
        {
            const int n = tid & 63, kg = tid >> 6;
            const float* src = W + (size_t)(k0 + kg * 8) * C + n0 + n;
            union { bf16x8 v; unsigned short u[8]; } p;
            #pragma unroll
            for (int j = 0; j < 8; ++j) p.u[j] = f2b(src[(size_t)j * C]);
            *(bf16x8*)&Bs[n * LSTR + kg * 8] = p.v;
        }
        __syncthreads();
        // ---- MFMA: wave quadrant 64x32 ----
        #pragma unroll
        for (int t = 0; t < 4; ++t) {
            const bf16x8 af = *(const bf16x8*)&As[(mw + t * 16 + l15) * LSTR + quad * 8];
            #pragma unroll
            for (int u = 0; u < 2; ++u) {
                const bf16x8 bfr = *(const bf16x8*)&Bs[(nw + u * 16 + l15) * LSTR + quad * 8];
                acc[t][u] = __builtin_amdgcn_mfma_f32_16x16x32_bf16(af, bfr, acc[t][u], 0, 0, 0);
            }
        }
    }

    // ---- epilogue: bias (+scale) (+RoPE) + head permute ----
    #pragma unroll
    for (int u = 0; u < 2; ++u) {
        const int col = n0 + nw + u * 16 + l15;       // 0..255 within this weight
        const int d = col & 31, head = col >> 5;
        const float bv_ = bias[col];
        #pragma unroll
        for (int t = 0; t < 4; ++t) {
            #pragma unroll
            for (int r = 0; r < 4; ++r) {
                const int R = row0 + mw + t * 16 + quad * 4 + r;
                const int b = R / L, l = R % L;
                float val = acc[t][u][r] + bv_;
                if (wsel == 2) {
                    v_perm[(((size_t)(b * NH + head)) * L + l) * HD + d] = val;
                } else {
                    if (wsel == 1) val *= 0.17677669529663689f;   // 32^-0.5
                    const float partner = __shfl_xor(val, 1);
                    const float rot = (d & 1) ? partner : -partner;
                    const float sn = sinp[l * HD + d];
                    const float cs = cosp[l * HD + d];
                    const unsigned short res = f2b(val * cs + rot * sn);
                    unsigned short* dst = (wsel == 1) ? k_bf : q_bf;
                    dst[(((size_t)(b * NH + head)) * L + l) * HD + d] = res;
                }
            }
        }
    }
}

// ---------------------------------------------------------------------------
// K1b: v_perm fp32 [bn][l][32] -> vt_bf bf16 [bn][32][l]
// ---------------------------------------------------------------------------
__global__ __launch_bounds__(256) void v_transpose(
    const float* __restrict__ v_perm, unsigned short* __restrict__ vt_bf)
{
    __shared__ float tile[32][33];
    const int t = threadIdx.x;
    const int bn = blockIdx.x / (L / 32);
    const int l0 = (blockIdx.x % (L / 32)) * 32;

    #pragma unroll
    for (int p = 0; p < 4; ++p) {
        const int row = p * 8 + (t >> 5), col = t & 31;
        tile[row][col] = v_perm[((size_t)bn * L + l0 + row) * HD + col];
    }
    __syncthreads();
    #pragma unroll
    for (int p = 0; p < 4; ++p) {
        const int d = p * 8 + (t >> 5), l = t & 31;
        vt_bf[((size_t)bn * HD + d) * L + l0 + l] = f2b(tile[l][d]);
    }
}

// ---------------------------------------------------------------------------
// K2: 5x5 depthwise conv on v, writes lepe [b][l][c]
// ---------------------------------------------------------------------------
__global__ __launch_bounds__(256) void dwconv(
    const float* __restrict__ v_perm,
    const float* __restrict__ w_dw, const float* __restrict__ b_dw,
    float* __restrict__ lepe)
{
    const int idx = blockIdx.x * 256 + threadIdx.x;
    const int c = idx & (C - 1);
    const int pix = idx >> 8;
    const int b = pix / L, l = pix % L;
    const int h = l / Ww, w = l % Ww;
    const int n = c >> 5, d = c & 31;

    const float* vb = v_perm + ((size_t)(b * NH + n)) * L * HD + d;
    float acc = b_dw[c];
    #pragma unroll
    for (int ky = 0; ky < 5; ++ky) {
        const int hy = h + ky - 2;
        if (hy < 0 || hy >= Hh) continue;
        #pragma unroll
        for (int kx = 0; kx < 5; ++kx) {
            const int wx = w + kx - 2;
            if (wx < 0 || wx >= Ww) continue;
            acc += vb[(size_t)(hy * Ww + wx) * HD] * w_dw[(ky * 5 + kx) * C + c];
        }
    }
    lepe[(size_t)pix * C + c] = acc;
}

// ---------------------------------------------------------------------------
// K3: flash MFMA attention, batch-merged, swapped QK^T.
//     R7: (a) INTERLEAVED wave key-chunks — wave w takes chunk it*4+w, so
//     per iteration the block reads a CONTIGUOUS 256-key band: mask =
//     16 rows x 1KB contiguous, K = 16KB contiguous, V = 32 rows x 1KB,
//     and successive iterations walk columns strictly sequentially.
//     The mask stream becomes 16 clean sequential streams per block
//     instead of 64 fragmented 256B windows. (Key-order of accumulation
//     changes; sums commute.)
//     (b) mask prefetch deepened to 2 iterations (3-buffer rotation).
// ---------------------------------------------------------------------------
__global__ __launch_bounds__(256) void attn_mfma(
    const unsigned short* __restrict__ q_bf,
    const unsigned short* __restrict__ k_bf,
    const unsigned short* __restrict__ vt_bf,
    const float* __restrict__ mask,
    float* __restrict__ attn_out)
{
    __shared__ __align__(16) unsigned short ps[4][2 * 16 * 72]; // per-wave, per-batch P
    __shared__ float obuf[2][4][16][32];                        // 16 KB partial O
    __shared__ float lbuf[2][4][16];                            // partial row sums

    const int tid  = threadIdx.x;
    const int wave = tid >> 6, lane = tid & 63;
    const int quad = lane >> 4, l15 = lane & 15;
    const int n  = blockIdx.x & 7;
    const int qt = blockIdx.x >> 3;
    const int q0 = qt * 16;

    const size_t bn0 = (size_t)n;        // batch 0
    const size_t bn1 = (size_t)(8 + n);  // batch 1

    // Q fragments (B-operand of swapped mfma): Q[q0+l15][quad*8 .. +7]
    const bf16x8 qa0 = *(const bf16x8*)(q_bf + ((bn0 * L + q0 + l15) * HD + quad * 8));
    const bf16x8 qa1 = *(const bf16x8*)(q_bf + ((bn1 * L + q0 + l15) * HD + quad * 8));

    const unsigned short* kg0 = k_bf  + bn0 * L * HD;
    const unsigned short* kg1 = k_bf  + bn1 * L * HD;
    const unsigned short* vg0 = vt_bf + bn0 * HD * L;   // [d][l]
    const unsigned short* vg1 = vt_bf + bn1 * HD * L;
    // per-lane mask row: mask[n][q0+l15][*]
    const float* mrow = mask + (size_t)n * L * L + (size_t)(q0 + l15) * L;

    f32x4 O00 = {0,0,0,0}, O01 = {0,0,0,0};   // batch0: d 0-15 / 16-31
    f32x4 O10 = {0,0,0,0}, O11 = {0,0,0,0};   // batch1
    float lrow0 = 0.f, lrow1 = 0.f;
    unsigned short* pw0 = &ps[wave][0];
    unsigned short* pw1 = &ps[wave][16 * 72];

    f32x4 mA[4], mB[4], mC[4];                // mask triple-buffer, 2-deep prefetch

#define CHUNK0(IT) (((IT) * 4 + wave) * 64)

#define PREFM(SET, IT) do {                                                   \
        const int mp0_ = CHUNK0(IT);                                          \
        _Pragma("unroll")                                                     \
        for (int t_ = 0; t_ < 4; ++t_)                                        \
            m##SET[t_] = *(const f32x4*)(mrow + mp0_ + t_ * 16 + quad * 4);   \
    } while (0)

#define KLOAD(DST, KGP, M0)                                                   \
        _Pragma("unroll")                                                     \
        for (int t_ = 0; t_ < 4; ++t_)                                        \
            DST[t_] = *(const bf16x8*)(KGP + ((size_t)((M0) + t_ * 16 + l15)) * HD + quad * 8);

#define VLOAD(DST, VGP, M0)                                                   \
        _Pragma("unroll")                                                     \
        for (int kh_ = 0; kh_ < 2; ++kh_) {                                   \
            DST[kh_ * 2 + 0] = *(const bf16x8*)(VGP + (size_t)l15 * L        + (M0) + kh_ * 32 + quad * 8); \
            DST[kh_ * 2 + 1] = *(const bf16x8*)(VGP + (size_t)(16 + l15) * L + (M0) + kh_ * 32 + quad * 8); \
        }

// one 64-key step for both batches; PREFSTMT issues next mask loads after K/V
#define COMP(MSET, IT, PREFSTMT) do {                                         \
        const int m0_ = CHUNK0(IT);                                           \
        bf16x8 kf0_[4], kf1_[4], vf0_[4], vf1_[4];                            \
        KLOAD(kf0_, kg0, m0_)                                                 \
        KLOAD(kf1_, kg1, m0_)                                                 \
        VLOAD(vf0_, vg0, m0_)                                                 \
        VLOAD(vf1_, vg1, m0_)                                                 \
        PREFSTMT;                                                             \
        { /* ---- batch 0 ---- */                                             \
            f32x4 S_[4]; const f32x4 z_ = {0,0,0,0};                          \
            _Pragma("unroll")                                                 \
            for (int t_ = 0; t_ < 4; ++t_)                                    \
                S_[t_] = __builtin_amdgcn_mfma_f32_16x16x32_bf16(kf0_[t_], qa0, z_, 0, 0, 0); \
            _Pragma("unroll")                                                 \
            for (int t_ = 0; t_ < 4; ++t_) {                                  \
                u16x4 pk_;                                                    \
                _Pragma("unroll")                                             \
                for (int r_ = 0; r_ < 4; ++r_) {                              \
                    const float p_ = __expf(S_[t_][r_] + m##MSET[t_][r_]);    \
                    lrow0 += p_;  pk_[r_] = f2b(p_);                          \
                }                                                             \
                *(u16x4*)&pw0[l15 * 72 + t_ * 16 + quad * 4] = pk_;           \
            }                                                                 \
            _Pragma("unroll")                                                 \
            for (int kh_ = 0; kh_ < 2; ++kh_) {                               \
                const bf16x8 pa_ = *(const bf16x8*)&pw0[l15 * 72 + kh_ * 32 + quad * 8]; \
                O00 = __builtin_amdgcn_mfma_f32_16x16x32_bf16(pa_, vf0_[kh_ * 2 + 0], O00, 0, 0, 0); \
                O01 = __builtin_amdgcn_mfma_f32_16x16x32_bf16(pa_, vf0_[kh_ * 2 + 1], O01, 0, 0, 0); \
            }                                                                 \
        }                                                                     \
        { /* ---- batch 1 ---- */                                             \
            f32x4 S_[4]; const f32x4 z_ = {0,0,0,0};                          \
            _Pragma("unroll")                                                 \
            for (int t_ = 0; t_ < 4; ++t_)                                    \
                S_[t_] = __builtin_amdgcn_mfma_f32_16x16x32_bf16(kf1_[t_], qa1, z_, 0, 0, 0); \
            _Pragma("unroll")                                                 \
            for (int t_ = 0; t_ < 4; ++t_) {                                  \
                u16x4 pk_;                                                    \
                _Pragma("unroll")                                             \
                for (int r_ = 0; r_ < 4; ++r_) {                              \
                    const float p_ = __expf(S_[t_][r_] + m##MSET[t_][r_]);    \
                    lrow1 += p_;  pk_[r_] = f2b(p_);                          \
                }                                                             \
                *(u16x4*)&pw1[l15 * 72 + t_ * 16 + quad * 4] = pk_;           \
            }                                                                 \
            _Pragma("unroll")                                                 \
            for (int kh_ = 0; kh_ < 2; ++kh_) {                               \
                const bf16x8 pa_ = *(const bf16x8*)&pw1[l15 * 72 + kh_ * 32 + quad * 8]; \
                O10 = __builtin_amdgcn_mfma_f32_16x16x32_bf16(pa_, vf1_[kh_ * 2 + 0], O10, 0, 0, 0); \
                O11 = __builtin_amdgcn_mfma_f32_16x16x32_bf16(pa_, vf1_[kh_ * 2 + 1], O11, 0, 0, 0); \
            }                                                                 \
        }                                                                     \
    } while (0)

    // 9 iterations of 64 keys per wave (block covers 256 contiguous keys per
    // iteration); mask prefetched TWO iterations ahead via A/B/C rotation.
    PREFM(A, 0);
    PREFM(B, 1);
    COMP(A, 0, PREFM(C, 2));
    COMP(B, 1, PREFM(A, 3));
    COMP(C, 2, PREFM(B, 4));
    COMP(A, 3, PREFM(C, 5));
    COMP(B, 4, PREFM(A, 6));
    COMP(C, 5, PREFM(B, 7));
    COMP(A, 6, PREFM(C, 8));
    COMP(B, 7, (void)0);
    COMP(C, 8, (void)0);

#undef CHUNK0
#undef PREFM
#undef KLOAD
#undef VLOAD
#undef COMP

    // ---- reduce row-sum across quads (lanes l15, l15+16, l15+32, l15+48) ----
    lrow0 += __shfl_xor(lrow0, 16);  lrow0 += __shfl_xor(lrow0, 32);
    lrow1 += __shfl_xor(lrow1, 16);  lrow1 += __shfl_xor(lrow1, 32);

    // ---- write wave partials (O layout: row=q=quad*4+r, col=d=l15 / 16+l15) ----
    #pragma unroll
    for (int r = 0; r < 4; ++r) {
        obuf[0][wave][quad * 4 + r][l15]      = O00[r];
        obuf[0][wave][quad * 4 + r][16 + l15] = O01[r];
        obuf[1][wave][quad * 4 + r][l15]      = O10[r];
        obuf[1][wave][quad * 4 + r][16 + l15] = O11[r];
    }
    if (lane < 16) {
        lbuf[0][wave][l15] = lrow0;
        lbuf[1][wave][l15] = lrow1;
    }
    __syncthreads();

    // ---- merge 4 wave partials, normalize, write fp32 [b][l][c] ----
    #pragma unroll
    for (int idx = tid; idx < 1024; idx += 256) {
        const int bsel = idx >> 9, row = (idx >> 5) & 15, col = idx & 31;
        const float o = obuf[bsel][0][row][col] + obuf[bsel][1][row][col]
                      + obuf[bsel][2][row][col] + obuf[bsel][3][row][col];
        const float lsum = lbuf[bsel][0][row] + lbuf[bsel][1][row]
                         + lbuf[bsel][2][row] + lbuf[bsel][3][row];
        attn_out[((size_t)bsel * L + q0 + row) * C + n * HD + col] = o / lsum;
    }
}

// ---------------------------------------------------------------------------
// K4: MFMA GEMM out = (attn_out + lepe) @ wo + bo.
//     Tile 64x64, grid 72 x 4.
// ---------------------------------------------------------------------------
__global__ __launch_bounds__(256) void gemm_out(
    const float* __restrict__ attn_out, const float* __restrict__ lepe,
    const float* __restrict__ wo, const float* __restrict__ bo,
    float* __restrict__ out)
{
    __shared__ __align__(16) unsigned short As[64 * LSTR];   // 5120 B
    __shared__ __align__(16) unsigned short Bs[64 * LSTR];   // 5120 B

    const int tid  = threadIdx.x;
    const int wave = tid >> 6, lane = tid & 63;
    const int quad = lane >> 4, l15 = lane & 15;
    const int mb = blockIdx.x % 72, nb = blockIdx.x / 72;
    const int row0 = mb * 64, n0 = nb * 64;
    const int mw = (wave & 1) * 32, nw = (wave >> 1) * 32;

    f32x4 acc[2][2];
    #pragma unroll
    for (int t = 0; t < 2; ++t)
        #pragma unroll
        for (int u = 0; u < 2; ++u) acc[t][u] = (f32x4){0,0,0,0};

    for (int kc = 0; kc < 8; ++kc) {
        const int k0 = kc * 32;
        __syncthreads();
        // ---- stage A: 64x32 of (attn_out + lepe). thread: row=tid>>2, q=tid&3
        {
            const int row = tid >> 2, qt = tid & 3;
            const size_t base = (size_t)(row0 + row) * C + k0 + qt * 8;
            #pragma unroll
            for (int j = 0; j < 2; ++j) {
                const f32x4 a = *(const f32x4*)(attn_out + base + j * 4);
                const f32x4 e = *(const f32x4*)(lepe + base + j * 4);
                u16x4 p = { f2b(a[0] + e[0]), f2b(a[1] + e[1]),
                            f2b(a[2] + e[2]), f2b(a[3] + e[3]) };
                *(u16x4*)&As[row * LSTR + qt * 8 + j * 4] = p;
            }
        }
        // ---- stage B transposed ----
        {
            const int n = tid & 63, kg = tid >> 6;
            const float* src = wo + (size_t)(k0 + kg * 8) * C + n0 + n;
            union { bf16x8 v; unsigned short u[8]; } p;
            #pragma unroll
            for (int j = 0; j < 8; ++j) p.u[j] = f2b(src[(size_t)j * C]);
            *(bf16x8*)&Bs[n * LSTR + kg * 8] = p.v;
        }
        __syncthreads();
        // ---- MFMA: wave quadrant 32x32 ----
        #pragma unroll
        for (int t = 0; t < 2; ++t) {
            const bf16x8 af = *(const bf16x8*)&As[(mw + t * 16 + l15) * LSTR + quad * 8];
            #pragma unroll
            for (int u = 0; u < 2; ++u) {
                const bf16x8 bfr = *(const bf16x8*)&Bs[(nw + u * 16 + l15) * LSTR + quad * 8];
                acc[t][u] = __builtin_amdgcn_mfma_f32_16x16x32_bf16(af, bfr, acc[t][u], 0, 0, 0);
            }
        }
    }

    // ---- epilogue: + bias, fp32 store ----
    #pragma unroll
    for (int u = 0; u < 2; ++u) {
        const int col = n0 + nw + u * 16 + l15;
        const float bv_ = bo[col];
        #pragma unroll
        for (int t = 0; t < 2; ++t)
            #pragma unroll
            for (int r = 0; r < 4; ++r) {
                const int R = row0 + mw + t * 16 + quad * 4 + r;
                out[(size_t)R * C + col] = acc[t][u][r] + bv_;
            }
    }
}

// ---------------------------------------------------------------------------
extern "C" void kernel_launch(void* const* d_in, const int* in_sizes, int n_in,
                              void* d_out, int out_size, void* d_ws, size_t ws_size,
                              hipStream_t stream)
{
    const float* x    = (const float*)d_in[0];
    const float* sinp = (const float*)d_in[1];
    const float* cosp = (const float*)d_in[2];
    const float* mask = (const float*)d_in[3];
    const float* wq   = (const float*)d_in[4];
    const float* bq   = (const float*)d_in[5];
    const float* wk   = (const float*)d_in[6];
    const float* bk   = (const float*)d_in[7];
    const float* wv   = (const float*)d_in[8];
    const float* bv   = (const float*)d_in[9];
    const float* w_dw = (const float*)d_in[10];
    const float* b_dw = (const float*)d_in[11];
    const float* wo   = (const float*)d_in[12];
    const float* bo   = (const float*)d_in[13];
    float* out = (float*)d_out;

    float* ws = (float*)d_ws;
    const size_t nqkv = (size_t)Bb * NH * L * HD;   // 1179648
    float* v_perm   = ws;                            // nqkv fp32
    float* lepe     = v_perm + nqkv;                 // NROW*C fp32
    float* attn_out = lepe + (size_t)NROW * C;       // NROW*C fp32
    unsigned short* q_bf  = (unsigned short*)(attn_out + (size_t)NROW * C);
    unsigned short* k_bf  = q_bf + nqkv;
    unsigned short* vt_bf = k_bf + nqkv;

    gemm_qkv<<<36 * 12, 256, 0, stream>>>(x, wq, bq, wk, bk, wv, bv,
                                          sinp, cosp, q_bf, k_bf, v_perm);
    v_transpose<<<Bb * NH * (L / 32), 256, 0, stream>>>(v_perm, vt_bf);
    dwconv<<<(Bb * L * C) / 256, 256, 0, stream>>>(v_perm, w_dw, b_dw, lepe);
    attn_mfma<<<(L / 16) * NH, 256, 0, stream>>>(q_bf, k_bf, vt_bf, mask, attn_out);
    gemm_out<<<72 * 4, 256, 0, stream>>>(attn_out, lepe, wo, bo, out);
}

// Round 5
// 353.695 us; speedup vs baseline: 1.0203x; 1.0203x over previous
//
#include <hip/hip_runtime.h>
#include <hip/hip_bf16.h>

#define Bb 2
#define Hh 48
#define Ww 48
#define C 256
#define NH 8
#define HD 32
#define L 2304          // 48*48
#define NROW (Bb*L)     // 4608

typedef short  bf16x8 __attribute__((ext_vector_type(8)));
typedef float  f32x4  __attribute__((ext_vector_type(4)));
typedef unsigned short u16x4 __attribute__((ext_vector_type(4)));

__device__ __forceinline__ unsigned short f2b(float f) {
    union { float f; unsigned int u; } v; v.f = f;
    unsigned int r = v.u + 0x7fff + ((v.u >> 16) & 1);   // RNE
    return (unsigned short)(r >> 16);
}

__device__ __forceinline__ f32x4 ldnt4(const float* p) {
    return __builtin_nontemporal_load((const f32x4*)p);
}

#define LSTR 40   // u16 stride of LDS tile rows (80 B: 16B-aligned, odd multiple of 16 -> <=2-way banks)

// ---------------------------------------------------------------------------
// K1: MFMA GEMM for QKV projection + bias + k-scale + RoPE + head permute.
//     Tile 128(M) x 64(N), K=256 in 8 chunks of 32. Grid 36 x 12.
//     nb>>2 selects weight (q,k,v); (nb&3)*64 is the column block.
// ---------------------------------------------------------------------------
__global__ __launch_bounds__(256) void gemm_qkv(
    const float* __restrict__ x,
    const float* __restrict__ wq, const float* __restrict__ bq,
    const float* __restrict__ wk, const float* __restrict__ bk,
    const float* __restrict__ wv, const float* __restrict__ bv,
    const float* __restrict__ sinp, const float* __restrict__ cosp,
    unsigned short* __restrict__ q_bf, unsigned short* __restrict__ k_bf,
    float* __restrict__ v_perm)
{
    __shared__ __align__(16) unsigned short As[128 * LSTR];  // 10240 B
    __shared__ __align__(16) unsigned short Bs[64 * LSTR];   //  5120 B

    const int tid  = threadIdx.x;
    const int wave = tid >> 6, lane = tid & 63;
    const int quad = lane >> 4, l15 = lane & 15;
    const int mb = blockIdx.x % 36, nb = blockIdx.x / 36;
    const int row0 = mb * 128;
    const int wsel = nb >> 2, n0 = (nb & 3) * 64;
    const float* W    = (wsel == 0) ? wq : (wsel == 1) ? wk : wv;
    const float* bias = (wsel == 0) ? bq : (wsel == 1) ? bk : bv;

    const int mw = (wave & 1) * 64, nw = (wave >> 1) * 32;

    f32x4 acc[4][2];
    #pragma unroll
    for (int t = 0; t < 4; ++t)
        #pragma unroll
        for (int u = 0; u < 2; ++u) acc[t][u] = (f32x4){0,0,0,0};

    for (int kc = 0; kc < 8; ++kc) {
        const int k0 = kc * 32;
        __syncthreads();
        // ---- stage A: 128x32 fp32 -> bf16 LDS. thread: row=tid>>1, half=tid&1
        {
            const int row = tid >> 1, h = tid & 1;
            const float* src = x + (size_t)(row0 + row) * C + k0 + h * 16;
            #pragma unroll
            for (int j = 0; j < 4; ++j) {
                const f32x4 v = *(const f32x4*)(src + j * 4);
                u16x4 p = { f2b(v[0]), f2b(v[1]), f2b(v[2]), f2b(v[3]) };
                *(u16x4*)&As[row * LSTR + h * 16 + j * 4] = p;
            }
        }
        // ---- stage B transposed: W[k0+k][n0+n] -> Bs[n][k]. thread: n=tid&63, kg=tid>>6
        {
            const int n = tid & 63, kg = tid >> 6;
            const float* src = W + (size_t)(k0 + kg * 8) * C + n0 + n;
            union { bf16x8 v; unsigned short u[8]; } p;
            #pragma unroll
            for (int j = 0; j < 8; ++j) p.u[j] = f2b(src[(size_t)j * C]);
            *(bf16x8*)&Bs[n * LSTR + kg * 8] = p.v;
        }
        __syncthreads();
        // ---- MFMA: wave quadrant 64x32 ----
        #pragma unroll
        for (int t = 0; t < 4; ++t) {
            const bf16x8 af = *(const bf16x8*)&As[(mw + t * 16 + l15) * LSTR + quad * 8];
            #pragma unroll
            for (int u = 0; u < 2; ++u) {
                const bf16x8 bfr = *(const bf16x8*)&Bs[(nw + u * 16 + l15) * LSTR + quad * 8];
                acc[t][u] = __builtin_amdgcn_mfma_f32_16x16x32_bf16(af, bfr, acc[t][u], 0, 0, 0);
            }
        }
    }

    // ---- epilogue: bias (+scale) (+RoPE) + head permute ----
    #pragma unroll
    for (int u = 0; u < 2; ++u) {
        const int col = n0 + nw + u * 16 + l15;       // 0..255 within this weight
        const int d = col & 31, head = col >> 5;
        const float bv_ = bias[col];
        #pragma unroll
        for (int t = 0; t < 4; ++t) {
            #pragma unroll
            for (int r = 0; r < 4; ++r) {
                const int R = row0 + mw + t * 16 + quad * 4 + r;
                const int b = R / L, l = R % L;
                float val = acc[t][u][r] + bv_;
                if (wsel == 2) {
                    v_perm[(((size_t)(b * NH + head)) * L + l) * HD + d] = val;
                } else {
                    if (wsel == 1) val *= 0.17677669529663689f;   // 32^-0.5
                    const float partner = __shfl_xor(val, 1);
                    const float rot = (d & 1) ? partner : -partner;
                    const float sn = sinp[l * HD + d];
                    const float cs = cosp[l * HD + d];
                    const unsigned short res = f2b(val * cs + rot * sn);
                    unsigned short* dst = (wsel == 1) ? k_bf : q_bf;
                    dst[(((size_t)(b * NH + head)) * L + l) * HD + d] = res;
                }
            }
        }
    }
}

// ---------------------------------------------------------------------------
// K1b: v_perm fp32 [bn][l][32] -> vt_bf bf16 [bn][32][l]
// ---------------------------------------------------------------------------
__global__ __launch_bounds__(256) void v_transpose(
    const float* __restrict__ v_perm, unsigned short* __restrict__ vt_bf)
{
    __shared__ float tile[32][33];
    const int t = threadIdx.x;
    const int bn = blockIdx.x / (L / 32);
    const int l0 = (blockIdx.x % (L / 32)) * 32;

    #pragma unroll
    for (int p = 0; p < 4; ++p) {
        const int row = p * 8 + (t >> 5), col = t & 31;
        tile[row][col] = v_perm[((size_t)bn * L + l0 + row) * HD + col];
    }
    __syncthreads();
    #pragma unroll
    for (int p = 0; p < 4; ++p) {
        const int d = p * 8 + (t >> 5), l = t & 31;
        vt_bf[((size_t)bn * HD + d) * L + l0 + l] = f2b(tile[l][d]);
    }
}

// ---------------------------------------------------------------------------
// K2: 5x5 depthwise conv on v, writes lepe [b][l][c]
// ---------------------------------------------------------------------------
__global__ __launch_bounds__(256) void dwconv(
    const float* __restrict__ v_perm,
    const float* __restrict__ w_dw, const float* __restrict__ b_dw,
    float* __restrict__ lepe)
{
    const int idx = blockIdx.x * 256 + threadIdx.x;
    const int c = idx & (C - 1);
    const int pix = idx >> 8;
    const int b = pix / L, l = pix % L;
    const int h = l / Ww, w = l % Ww;
    const int n = c >> 5, d = c & 31;

    const float* vb = v_perm + ((size_t)(b * NH + n)) * L * HD + d;
    float acc = b_dw[c];
    #pragma unroll
    for (int ky = 0; ky < 5; ++ky) {
        const int hy = h + ky - 2;
        if (hy < 0 || hy >= Hh) continue;
        #pragma unroll
        for (int kx = 0; kx < 5; ++kx) {
            const int wx = w + kx - 2;
            if (wx < 0 || wx >= Ww) continue;
            acc += vb[(size_t)(hy * Ww + wx) * HD] * w_dw[(ky * 5 + kx) * C + c];
        }
    }
    lepe[(size_t)pix * C + c] = acc;
}

// ---------------------------------------------------------------------------
// K3: flash MFMA attention, batch-merged, swapped QK^T.
//     R9 = R8 with LDS overlay fix:
//     (a) Q-tile 32 — block count halves (1152->576), K/V L2-request volume
//         halves (680->340 MB/dispatch).
//     (b) non-temporal mask loads — read-once mask stream no longer evicts
//         the L2-resident K/V working set.
//     (c) wave-private 576-key chunks (R6 order; R7 interleave regressed).
//     (d) OVERLAY: P-scratch (loop-phase) and O-merge buffers (epilogue-
//         phase) share one 36864 B LDS arena — R8's 70656 B static LDS
//         (likely the launch failure) drops to 36864 B, 4 blocks/CU.
//         A __syncthreads() separates the two lifetimes.
// ---------------------------------------------------------------------------
__global__ __launch_bounds__(256) void attn_mfma(
    const unsigned short* __restrict__ q_bf,
    const unsigned short* __restrict__ k_bf,
    const unsigned short* __restrict__ vt_bf,
    const float* __restrict__ mask,
    float* __restrict__ attn_out)
{
    // one arena, two lifetimes:
    //   loop:     ps[wave][b*2+qh][16*72] u16   = 36864 B
    //   epilogue: obuf[2][4][32][32] f32 (32768) + lbuf[2][4][32] f32 (1024)
    __shared__ __align__(16) unsigned char smem[4 * 4 * 16 * 72 * 2]; // 36864 B

    const int tid  = threadIdx.x;
    const int wave = tid >> 6, lane = tid & 63;
    const int quad = lane >> 4, l15 = lane & 15;
    const int n  = blockIdx.x & 7;
    const int qt = blockIdx.x >> 3;
    const int q0 = qt * 32;

    const unsigned short* kg[2] = { k_bf  + (size_t)n * L * HD,
                                    k_bf  + (size_t)(8 + n) * L * HD };
    const unsigned short* vg[2] = { vt_bf + (size_t)n * HD * L,       // [d][l]
                                    vt_bf + (size_t)(8 + n) * HD * L };

    // Q fragments (B-operand of swapped mfma): [batch][q-half]
    bf16x8 qa[2][2];
    #pragma unroll
    for (int b = 0; b < 2; ++b)
        #pragma unroll
        for (int qh = 0; qh < 2; ++qh)
            qa[b][qh] = *(const bf16x8*)(q_bf +
                (((size_t)(b * 8 + n) * L + q0 + qh * 16 + l15) * HD + quad * 8));

    // per-lane mask rows: mask[n][q0+qh*16+l15][*]  (shared by both batches)
    const float* mrow[2];
    mrow[0] = mask + (size_t)n * L * L + (size_t)(q0 + l15) * L;
    mrow[1] = mrow[0] + (size_t)16 * L;

    f32x4 O[2][2][2];   // [batch][q-half][d-half]
    #pragma unroll
    for (int b = 0; b < 2; ++b)
        #pragma unroll
        for (int qh = 0; qh < 2; ++qh)
            #pragma unroll
            for (int dh = 0; dh < 2; ++dh) O[b][qh][dh] = (f32x4){0,0,0,0};
    float lrow[2][2] = {{0.f, 0.f}, {0.f, 0.f}};

    unsigned short* ps_wave = (unsigned short*)smem + (size_t)wave * 4 * 16 * 72;

    const int m_begin = wave * (L / 4);          // 576 keys per wave

    f32x4 mA[2][4], mB[2][4];                    // mask double-buffer [qh][t]

#define PREFM(SET, IT) do {                                                   \
        const int mp0_ = m_begin + (IT) * 64;                                 \
        _Pragma("unroll")                                                     \
        for (int qh_ = 0; qh_ < 2; ++qh_)                                     \
            _Pragma("unroll")                                                 \
            for (int t_ = 0; t_ < 4; ++t_)                                    \
                m##SET[qh_][t_] = ldnt4(mrow[qh_] + mp0_ + t_ * 16 + quad * 4); \
    } while (0)

// one 64-key step: both batches x both q-halves. PREFSTMT after K/V issue.
#define COMP(MSET, IT, PREFSTMT) do {                                         \
        const int m0_ = m_begin + (IT) * 64;                                  \
        bf16x8 kf_[2][4], vf_[2][4];                                          \
        _Pragma("unroll")                                                     \
        for (int b_ = 0; b_ < 2; ++b_)                                        \
            _Pragma("unroll")                                                 \
            for (int t_ = 0; t_ < 4; ++t_)                                    \
                kf_[b_][t_] = *(const bf16x8*)(kg[b_] +                       \
                    ((size_t)(m0_ + t_ * 16 + l15)) * HD + quad * 8);         \
        _Pragma("unroll")                                                     \
        for (int b_ = 0; b_ < 2; ++b_)                                        \
            _Pragma("unroll")                                                 \
            for (int kh_ = 0; kh_ < 2; ++kh_) {                               \
                vf_[b_][kh_ * 2 + 0] = *(const bf16x8*)(vg[b_] +              \
                    (size_t)l15 * L        + m0_ + kh_ * 32 + quad * 8);      \
                vf_[b_][kh_ * 2 + 1] = *(const bf16x8*)(vg[b_] +              \
                    (size_t)(16 + l15) * L + m0_ + kh_ * 32 + quad * 8);      \
            }                                                                 \
        PREFSTMT;                                                             \
        _Pragma("unroll")                                                     \
        for (int b_ = 0; b_ < 2; ++b_) {                                      \
            _Pragma("unroll")                                                 \
            for (int qh_ = 0; qh_ < 2; ++qh_) {                               \
                unsigned short* pw_ = ps_wave + (b_ * 2 + qh_) * 16 * 72;     \
                f32x4 S_[4]; const f32x4 z_ = {0,0,0,0};                      \
                _Pragma("unroll")                                             \
                for (int t_ = 0; t_ < 4; ++t_)                                \
                    S_[t_] = __builtin_amdgcn_mfma_f32_16x16x32_bf16(         \
                        kf_[b_][t_], qa[b_][qh_], z_, 0, 0, 0);               \
                _Pragma("unroll")                                             \
                for (int t_ = 0; t_ < 4; ++t_) {                              \
                    u16x4 pk_;                                                \
                    _Pragma("unroll")                                         \
                    for (int r_ = 0; r_ < 4; ++r_) {                          \
                        const float p_ = __expf(S_[t_][r_] + m##MSET[qh_][t_][r_]); \
                        lrow[b_][qh_] += p_;  pk_[r_] = f2b(p_);              \
                    }                                                         \
                    *(u16x4*)&pw_[l15 * 72 + t_ * 16 + quad * 4] = pk_;       \
                }                                                             \
                _Pragma("unroll")                                             \
                for (int kh_ = 0; kh_ < 2; ++kh_) {                           \
                    const bf16x8 pa_ = *(const bf16x8*)&pw_[l15 * 72 + kh_ * 32 + quad * 8]; \
                    O[b_][qh_][0] = __builtin_amdgcn_mfma_f32_16x16x32_bf16(  \
                        pa_, vf_[b_][kh_ * 2 + 0], O[b_][qh_][0], 0, 0, 0);   \
                    O[b_][qh_][1] = __builtin_amdgcn_mfma_f32_16x16x32_bf16(  \
                        pa_, vf_[b_][kh_ * 2 + 1], O[b_][qh_][1], 0, 0, 0);   \
                }                                                             \
            }                                                                 \
        }                                                                     \
    } while (0)

    // 9 iterations of 64 keys per wave; mask prefetched one iteration ahead.
    PREFM(A, 0);
    for (int p = 0; p < 4; ++p) {
        COMP(A, 2 * p,     PREFM(B, 2 * p + 1));
        COMP(B, 2 * p + 1, PREFM(A, 2 * p + 2));
    }
    COMP(A, 8, (void)0);

#undef PREFM
#undef COMP

    // ---- reduce row-sum across quads (lanes l15, l15+16, l15+32, l15+48) ----
    #pragma unroll
    for (int b = 0; b < 2; ++b)
        #pragma unroll
        for (int qh = 0; qh < 2; ++qh) {
            lrow[b][qh] += __shfl_xor(lrow[b][qh], 16);
            lrow[b][qh] += __shfl_xor(lrow[b][qh], 32);
        }

    // ---- lifetime switch: everyone done with P-scratch before obuf overlay ----
    __syncthreads();

    float* obuf = (float*)smem;                    // [b][wave][32][32]
    float* lbuf = (float*)(smem + 32768);          // [b][wave][32]

    // ---- write wave partials (row = q = qh*16+quad*4+r, col = d) ----
    #pragma unroll
    for (int b = 0; b < 2; ++b)
        #pragma unroll
        for (int qh = 0; qh < 2; ++qh)
            #pragma unroll
            for (int r = 0; r < 4; ++r) {
                const int row = qh * 16 + quad * 4 + r;
                obuf[(((size_t)b * 4 + wave) * 32 + row) * 32 + l15]      = O[b][qh][0][r];
                obuf[(((size_t)b * 4 + wave) * 32 + row) * 32 + 16 + l15] = O[b][qh][1][r];
            }
    if (lane < 16) {
        #pragma unroll
        for (int b = 0; b < 2; ++b)
            #pragma unroll
            for (int qh = 0; qh < 2; ++qh)
                lbuf[((size_t)b * 4 + wave) * 32 + qh * 16 + l15] = lrow[b][qh];
    }
    __syncthreads();

    // ---- merge 4 wave partials, normalize, write fp32 [b][l][c] ----
    #pragma unroll
    for (int idx = tid; idx < 2048; idx += 256) {
        const int bsel = idx >> 10, row = (idx >> 5) & 31, col = idx & 31;
        float o = 0.f, lsum = 0.f;
        #pragma unroll
        for (int w = 0; w < 4; ++w) {
            o    += obuf[(((size_t)bsel * 4 + w) * 32 + row) * 32 + col];
            lsum += lbuf[((size_t)bsel * 4 + w) * 32 + row];
        }
        attn_out[((size_t)bsel * L + q0 + row) * C + n * HD + col] = o / lsum;
    }
}

// ---------------------------------------------------------------------------
// K4: MFMA GEMM out = (attn_out + lepe) @ wo + bo.
//     Tile 64x64, grid 72 x 4.
// ---------------------------------------------------------------------------
__global__ __launch_bounds__(256) void gemm_out(
    const float* __restrict__ attn_out, const float* __restrict__ lepe,
    const float* __restrict__ wo, const float* __restrict__ bo,
    float* __restrict__ out)
{
    __shared__ __align__(16) unsigned short As[64 * LSTR];   // 5120 B
    __shared__ __align__(16) unsigned short Bs[64 * LSTR];   // 5120 B

    const int tid  = threadIdx.x;
    const int wave = tid >> 6, lane = tid & 63;
    const int quad = lane >> 4, l15 = lane & 15;
    const int mb = blockIdx.x % 72, nb = blockIdx.x / 72;
    const int row0 = mb * 64, n0 = nb * 64;
    const int mw = (wave & 1) * 32, nw = (wave >> 1) * 32;

    f32x4 acc[2][2];
    #pragma unroll
    for (int t = 0; t < 2; ++t)
        #pragma unroll
        for (int u = 0; u < 2; ++u) acc[t][u] = (f32x4){0,0,0,0};

    for (int kc = 0; kc < 8; ++kc) {
        const int k0 = kc * 32;
        __syncthreads();
        // ---- stage A: 64x32 of (attn_out + lepe). thread: row=tid>>2, q=tid&3
        {
            const int row = tid >> 2, qt = tid & 3;
            const size_t base = (size_t)(row0 + row) * C + k0 + qt * 8;
            #pragma unroll
            for (int j = 0; j < 2; ++j) {
                const f32x4 a = *(const f32x4*)(attn_out + base + j * 4);
                const f32x4 e = *(const f32x4*)(lepe + base + j * 4);
                u16x4 p = { f2b(a[0] + e[0]), f2b(a[1] + e[1]),
                            f2b(a[2] + e[2]), f2b(a[3] + e[3]) };
                *(u16x4*)&As[row * LSTR + qt * 8 + j * 4] = p;
            }
        }
        // ---- stage B transposed ----
        {
            const int n = tid & 63, kg = tid >> 6;
            const float* src = wo + (size_t)(k0 + kg * 8) * C + n0 + n;
            union { bf16x8 v; unsigned short u[8]; } p;
            #pragma unroll
            for (int j = 0; j < 8; ++j) p.u[j] = f2b(src[(size_t)j * C]);
            *(bf16x8*)&Bs[n * LSTR + kg * 8] = p.v;
        }
        __syncthreads();
        // ---- MFMA: wave quadrant 32x32 ----
        #pragma unroll
        for (int t = 0; t < 2; ++t) {
            const bf16x8 af = *(const bf16x8*)&As[(mw + t * 16 + l15) * LSTR + quad * 8];
            #pragma unroll
            for (int u = 0; u < 2; ++u) {
                const bf16x8 bfr = *(const bf16x8*)&Bs[(nw + u * 16 + l15) * LSTR + quad * 8];
                acc[t][u] = __builtin_amdgcn_mfma_f32_16x16x32_bf16(af, bfr, acc[t][u], 0, 0, 0);
            }
        }
    }

    // ---- epilogue: + bias, fp32 store ----
    #pragma unroll
    for (int u = 0; u < 2; ++u) {
        const int col = n0 + nw + u * 16 + l15;
        const float bv_ = bo[col];
        #pragma unroll
        for (int t = 0; t < 2; ++t)
            #pragma unroll
            for (int r = 0; r < 4; ++r) {
                const int R = row0 + mw + t * 16 + quad * 4 + r;
                out[(size_t)R * C + col] = acc[t][u][r] + bv_;
            }
    }
}

// ---------------------------------------------------------------------------
extern "C" void kernel_launch(void* const* d_in, const int* in_sizes, int n_in,
                              void* d_out, int out_size, void* d_ws, size_t ws_size,
                              hipStream_t stream)
{
    const float* x    = (const float*)d_in[0];
    const float* sinp = (const float*)d_in[1];
    const float* cosp = (const float*)d_in[2];
    const float* mask = (const float*)d_in[3];
    const float* wq   = (const float*)d_in[4];
    const float* bq   = (const float*)d_in[5];
    const float* wk   = (const float*)d_in[6];
    const float* bk   = (const float*)d_in[7];
    const float* wv   = (const float*)d_in[8];
    const float* bv   = (const float*)d_in[9];
    const float* w_dw = (const float*)d_in[10];
    const float* b_dw = (const float*)d_in[11];
    const float* wo   = (const float*)d_in[12];
    const float* bo   = (const float*)d_in[13];
    float* out = (float*)d_out;

    float* ws = (float*)d_ws;
    const size_t nqkv = (size_t)Bb * NH * L * HD;   // 1179648
    float* v_perm   = ws;                            // nqkv fp32
    float* lepe     = v_perm + nqkv;                 // NROW*C fp32
    float* attn_out = lepe + (size_t)NROW * C;       // NROW*C fp32
    unsigned short* q_bf  = (unsigned short*)(attn_out + (size_t)NROW * C);
    unsigned short* k_bf  = q_bf + nqkv;
    unsigned short* vt_bf = k_bf + nqkv;

    gemm_qkv<<<36 * 12, 256, 0, stream>>>(x, wq, bq, wk, bk, wv, bv,
                                          sinp, cosp, q_bf, k_bf, v_perm);
    v_transpose<<<Bb * NH * (L / 32), 256, 0, stream>>>(v_perm, vt_bf);
    dwconv<<<(Bb * L * C) / 256, 256, 0, stream>>>(v_perm, w_dw, b_dw, lepe);
    attn_mfma<<<(L / 32) * NH, 256, 0, stream>>>(q_bf, k_bf, vt_bf, mask, attn_out);
    gemm_out<<<72 * 4, 256, 0, stream>>>(attn_out, lepe, wo, bo, out);
}

// Round 7
// 349.550 us; speedup vs baseline: 1.0324x; 1.0119x over previous
//
#include <hip/hip_runtime.h>
#include <hip/hip_bf16.h>

#define Bb 2
#define Hh 48
#define Ww 48
#define C 256
#define NH 8
#define HD 32
#define L 2304          // 48*48
#define NROW (Bb*L)     // 4608

typedef short  bf16x8 __attribute__((ext_vector_type(8)));
typedef float  f32x4  __attribute__((ext_vector_type(4)));
typedef unsigned short u16x4 __attribute__((ext_vector_type(4)));

__device__ __forceinline__ unsigned short f2b(float f) {
    union { float f; unsigned int u; } v; v.f = f;
    unsigned int r = v.u + 0x7fff + ((v.u >> 16) & 1);   // RNE
    return (unsigned short)(r >> 16);
}

__device__ __forceinline__ f32x4 ldnt4(const float* p) {
    return __builtin_nontemporal_load((const f32x4*)p);
}

#define LSTR 40   // u16 stride of LDS tile rows (80 B: 16B-aligned, odd multiple of 16 -> <=2-way banks)

// ---------------------------------------------------------------------------
// K0 (prep): one-shot bf16 conversions so the GEMMs never re-convert.
//   blocks [0,1152):  x fp32 -> x_bf bf16 (same [row][k] layout)
//   blocks [1152,1408): wq/wk/wv/wo -> wt_bf[wsel][n][k] = W[k][n] (bf16, transposed)
// ---------------------------------------------------------------------------
__global__ __launch_bounds__(256) void prep(
    const float* __restrict__ x,
    const float* __restrict__ wq, const float* __restrict__ wk,
    const float* __restrict__ wv, const float* __restrict__ wo,
    unsigned short* __restrict__ x_bf, unsigned short* __restrict__ wt_bf)
{
    __shared__ float t[32][33];
    const int tid = threadIdx.x;
    int bid = blockIdx.x;
    if (bid < 1152) {
        const size_t base = (size_t)bid * 1024 + tid * 4;
        const f32x4 v = *(const f32x4*)(x + base);
        u16x4 p = { f2b(v[0]), f2b(v[1]), f2b(v[2]), f2b(v[3]) };
        *(u16x4*)&x_bf[base] = p;
    } else {
        bid -= 1152;
        const int wsel = bid >> 6, tile = bid & 63;
        const int trow = (tile >> 3) * 32, tcol = (tile & 7) * 32;  // row=k, col=n
        const float* W = (wsel == 0) ? wq : (wsel == 1) ? wk : (wsel == 2) ? wv : wo;
        #pragma unroll
        for (int p = 0; p < 4; ++p) {
            const int r = p * 8 + (tid >> 5), c = tid & 31;
            t[r][c] = W[(size_t)(trow + r) * 256 + tcol + c];
        }
        __syncthreads();
        #pragma unroll
        for (int p = 0; p < 4; ++p) {
            const int d = p * 8 + (tid >> 5), l = tid & 31;   // d=n offset, l=k offset
            wt_bf[(size_t)wsel * 65536 + (size_t)(tcol + d) * 256 + trow + l] = f2b(t[l][d]);
        }
    }
}

// ---------------------------------------------------------------------------
// K1: MFMA GEMM for QKV projection + bias + k-scale + RoPE + head permute.
//     Tile 128(M) x 64(N), K=256 in 8 chunks of 32. Grid 36 x 12.
//     R11: stages A from x_bf and B from wt_bf (prep output) — staging is
//     now pure bf16x8 copies: VMEM/thread/kc 12 -> 3, f2b 24 -> 0.
// ---------------------------------------------------------------------------
__global__ __launch_bounds__(256) void gemm_qkv(
    const unsigned short* __restrict__ x_bf,
    const unsigned short* __restrict__ wt_bf,
    const float* __restrict__ bq, const float* __restrict__ bk,
    const float* __restrict__ bv,
    const float* __restrict__ sinp, const float* __restrict__ cosp,
    unsigned short* __restrict__ q_bf, unsigned short* __restrict__ k_bf,
    float* __restrict__ v_perm)
{
    __shared__ __align__(16) unsigned short As[128 * LSTR];  // 10240 B
    __shared__ __align__(16) unsigned short Bs[64 * LSTR];   //  5120 B

    const int tid  = threadIdx.x;
    const int wave = tid >> 6, lane = tid & 63;
    const int quad = lane >> 4, l15 = lane & 15;
    const int mb = blockIdx.x % 36, nb = blockIdx.x / 36;
    const int row0 = mb * 128;
    const int wsel = nb >> 2, n0 = (nb & 3) * 64;
    const float* bias = (wsel == 0) ? bq : (wsel == 1) ? bk : bv;
    const unsigned short* wt = wt_bf + (size_t)wsel * 65536;

    const int mw = (wave & 1) * 64, nw = (wave >> 1) * 32;

    f32x4 acc[4][2];
    #pragma unroll
    for (int t = 0; t < 4; ++t)
        #pragma unroll
        for (int u = 0; u < 2; ++u) acc[t][u] = (f32x4){0,0,0,0};

    for (int kc = 0; kc < 8; ++kc) {
        const int k0 = kc * 32;
        __syncthreads();
        // ---- stage A: 128x32 bf16 copy. thread: row=tid>>1, half=tid&1
        {
            const int row = tid >> 1, h = tid & 1;
            const unsigned short* src = x_bf + (size_t)(row0 + row) * C + k0 + h * 16;
            *(bf16x8*)&As[row * LSTR + h * 16]     = *(const bf16x8*)(src);
            *(bf16x8*)&As[row * LSTR + h * 16 + 8] = *(const bf16x8*)(src + 8);
        }
        // ---- stage B: 64x32 bf16 copy from wt[n][k]. thread: n=tid>>2, kq=tid&3
        {
            const int n = tid >> 2, kq = tid & 3;
            const unsigned short* src = wt + (size_t)(n0 + n) * 256 + k0 + kq * 8;
            *(bf16x8*)&Bs[n * LSTR + kq * 8] = *(const bf16x8*)src;
        }
        __syncthreads();
        // ---- MFMA: wave quadrant 64x32 ----
        #pragma unroll
        for (int t = 0; t < 4; ++t) {
            const bf16x8 af = *(const bf16x8*)&As[(mw + t * 16 + l15) * LSTR + quad * 8];
            #pragma unroll
            for (int u = 0; u < 2; ++u) {
                const bf16x8 bfr = *(const bf16x8*)&Bs[(nw + u * 16 + l15) * LSTR + quad * 8];
                acc[t][u] = __builtin_amdgcn_mfma_f32_16x16x32_bf16(af, bfr, acc[t][u], 0, 0, 0);
            }
        }
    }

    // ---- epilogue: bias (+scale) (+RoPE) + head permute ----
    #pragma unroll
    for (int u = 0; u < 2; ++u) {
        const int col = n0 + nw + u * 16 + l15;       // 0..255 within this weight
        const int d = col & 31, head = col >> 5;
        const float bv_ = bias[col];
        #pragma unroll
        for (int t = 0; t < 4; ++t) {
            #pragma unroll
            for (int r = 0; r < 4; ++r) {
                const int R = row0 + mw + t * 16 + quad * 4 + r;
                const int b = R / L, l = R % L;
                float val = acc[t][u][r] + bv_;
                if (wsel == 2) {
                    v_perm[(((size_t)(b * NH + head)) * L + l) * HD + d] = val;
                } else {
                    if (wsel == 1) val *= 0.17677669529663689f;   // 32^-0.5
                    const float partner = __shfl_xor(val, 1);
                    const float rot = (d & 1) ? partner : -partner;
                    const float sn = sinp[l * HD + d];
                    const float cs = cosp[l * HD + d];
                    const unsigned short res = f2b(val * cs + rot * sn);
                    unsigned short* dst = (wsel == 1) ? k_bf : q_bf;
                    dst[(((size_t)(b * NH + head)) * L + l) * HD + d] = res;
                }
            }
        }
    }
}

// ---------------------------------------------------------------------------
// K1b: v_perm fp32 [bn][l][32] -> vt_bf bf16 [bn][32][l]
// ---------------------------------------------------------------------------
__global__ __launch_bounds__(256) void v_transpose(
    const float* __restrict__ v_perm, unsigned short* __restrict__ vt_bf)
{
    __shared__ float tile[32][33];
    const int t = threadIdx.x;
    const int bn = blockIdx.x / (L / 32);
    const int l0 = (blockIdx.x % (L / 32)) * 32;

    #pragma unroll
    for (int p = 0; p < 4; ++p) {
        const int row = p * 8 + (t >> 5), col = t & 31;
        tile[row][col] = v_perm[((size_t)bn * L + l0 + row) * HD + col];
    }
    __syncthreads();
    #pragma unroll
    for (int p = 0; p < 4; ++p) {
        const int d = p * 8 + (t >> 5), l = t & 31;
        vt_bf[((size_t)bn * HD + d) * L + l0 + l] = f2b(tile[l][d]);
    }
}

// ---------------------------------------------------------------------------
// K2: 5x5 depthwise conv on v, writes lepe [b][l][c]
// ---------------------------------------------------------------------------
__global__ __launch_bounds__(256) void dwconv(
    const float* __restrict__ v_perm,
    const float* __restrict__ w_dw, const float* __restrict__ b_dw,
    float* __restrict__ lepe)
{
    const int idx = blockIdx.x * 256 + threadIdx.x;
    const int c = idx & (C - 1);
    const int pix = idx >> 8;
    const int b = pix / L, l = pix % L;
    const int h = l / Ww, w = l % Ww;
    const int n = c >> 5, d = c & 31;

    const float* vb = v_perm + ((size_t)(b * NH + n)) * L * HD + d;
    float acc = b_dw[c];
    #pragma unroll
    for (int ky = 0; ky < 5; ++ky) {
        const int hy = h + ky - 2;
        if (hy < 0 || hy >= Hh) continue;
        #pragma unroll
        for (int kx = 0; kx < 5; ++kx) {
            const int wx = w + kx - 2;
            if (wx < 0 || wx >= Ww) continue;
            acc += vb[(size_t)(hy * Ww + wx) * HD] * w_dw[(ky * 5 + kx) * C + c];
        }
    }
    lepe[(size_t)pix * C + c] = acc;
}

// ---------------------------------------------------------------------------
// K3: flash MFMA attention, batch-merged, swapped QK^T (R9 known-good).
//     Q-tile 32, nt mask loads, wave-private 576-key chunks, LDS overlay.
// ---------------------------------------------------------------------------
__global__ __launch_bounds__(256) void attn_mfma(
    const unsigned short* __restrict__ q_bf,
    const unsigned short* __restrict__ k_bf,
    const unsigned short* __restrict__ vt_bf,
    const float* __restrict__ mask,
    float* __restrict__ attn_out)
{
    // one arena, two lifetimes:
    //   loop:     ps[wave][b*2+qh][16*72] u16   = 36864 B
    //   epilogue: obuf[2][4][32][32] f32 (32768) + lbuf[2][4][32] f32 (1024)
    __shared__ __align__(16) unsigned char smem[4 * 4 * 16 * 72 * 2]; // 36864 B

    const int tid  = threadIdx.x;
    const int wave = tid >> 6, lane = tid & 63;
    const int quad = lane >> 4, l15 = lane & 15;
    const int n  = blockIdx.x & 7;
    const int qt = blockIdx.x >> 3;
    const int q0 = qt * 32;

    const unsigned short* kg[2] = { k_bf  + (size_t)n * L * HD,
                                    k_bf  + (size_t)(8 + n) * L * HD };
    const unsigned short* vg[2] = { vt_bf + (size_t)n * HD * L,       // [d][l]
                                    vt_bf + (size_t)(8 + n) * HD * L };

    // Q fragments (B-operand of swapped mfma): [batch][q-half]
    bf16x8 qa[2][2];
    #pragma unroll
    for (int b = 0; b < 2; ++b)
        #pragma unroll
        for (int qh = 0; qh < 2; ++qh)
            qa[b][qh] = *(const bf16x8*)(q_bf +
                (((size_t)(b * 8 + n) * L + q0 + qh * 16 + l15) * HD + quad * 8));

    // per-lane mask rows: mask[n][q0+qh*16+l15][*]  (shared by both batches)
    const float* mrow[2];
    mrow[0] = mask + (size_t)n * L * L + (size_t)(q0 + l15) * L;
    mrow[1] = mrow[0] + (size_t)16 * L;

    f32x4 O[2][2][2];   // [batch][q-half][d-half]
    #pragma unroll
    for (int b = 0; b < 2; ++b)
        #pragma unroll
        for (int qh = 0; qh < 2; ++qh)
            #pragma unroll
            for (int dh = 0; dh < 2; ++dh) O[b][qh][dh] = (f32x4){0,0,0,0};
    float lrow[2][2] = {{0.f, 0.f}, {0.f, 0.f}};

    unsigned short* ps_wave = (unsigned short*)smem + (size_t)wave * 4 * 16 * 72;

    const int m_begin = wave * (L / 4);          // 576 keys per wave

    f32x4 mA[2][4], mB[2][4];                    // mask double-buffer [qh][t]

#define PREFM(SET, IT) do {                                                   \
        const int mp0_ = m_begin + (IT) * 64;                                 \
        _Pragma("unroll")                                                     \
        for (int qh_ = 0; qh_ < 2; ++qh_)                                     \
            _Pragma("unroll")                                                 \
            for (int t_ = 0; t_ < 4; ++t_)                                    \
                m##SET[qh_][t_] = ldnt4(mrow[qh_] + mp0_ + t_ * 16 + quad * 4); \
    } while (0)

// one 64-key step: both batches x both q-halves. PREFSTMT after K/V issue.
#define COMP(MSET, IT, PREFSTMT) do {                                         \
        const int m0_ = m_begin + (IT) * 64;                                  \
        bf16x8 kf_[2][4], vf_[2][4];                                          \
        _Pragma("unroll")                                                     \
        for (int b_ = 0; b_ < 2; ++b_)                                        \
            _Pragma("unroll")                                                 \
            for (int t_ = 0; t_ < 4; ++t_)                                    \
                kf_[b_][t_] = *(const bf16x8*)(kg[b_] +                       \
                    ((size_t)(m0_ + t_ * 16 + l15)) * HD + quad * 8);         \
        _Pragma("unroll")                                                     \
        for (int b_ = 0; b_ < 2; ++b_)                                        \
            _Pragma("unroll")                                                 \
            for (int kh_ = 0; kh_ < 2; ++kh_) {                               \
                vf_[b_][kh_ * 2 + 0] = *(const bf16x8*)(vg[b_] +              \
                    (size_t)l15 * L        + m0_ + kh_ * 32 + quad * 8);      \
                vf_[b_][kh_ * 2 + 1] = *(const bf16x8*)(vg[b_] +              \
                    (size_t)(16 + l15) * L + m0_ + kh_ * 32 + quad * 8);      \
            }                                                                 \
        PREFSTMT;                                                             \
        _Pragma("unroll")                                                     \
        for (int b_ = 0; b_ < 2; ++b_) {                                      \
            _Pragma("unroll")                                                 \
            for (int qh_ = 0; qh_ < 2; ++qh_) {                               \
                unsigned short* pw_ = ps_wave + (b_ * 2 + qh_) * 16 * 72;     \
                f32x4 S_[4]; const f32x4 z_ = {0,0,0,0};                      \
                _Pragma("unroll")                                             \
                for (int t_ = 0; t_ < 4; ++t_)                                \
                    S_[t_] = __builtin_amdgcn_mfma_f32_16x16x32_bf16(         \
                        kf_[b_][t_], qa[b_][qh_], z_, 0, 0, 0);               \
                _Pragma("unroll")                                             \
                for (int t_ = 0; t_ < 4; ++t_) {                              \
                    u16x4 pk_;                                                \
                    _Pragma("unroll")                                         \
                    for (int r_ = 0; r_ < 4; ++r_) {                          \
                        const float p_ = __expf(S_[t_][r_] + m##MSET[qh_][t_][r_]); \
                        lrow[b_][qh_] += p_;  pk_[r_] = f2b(p_);              \
                    }                                                         \
                    *(u16x4*)&pw_[l15 * 72 + t_ * 16 + quad * 4] = pk_;       \
                }                                                             \
                _Pragma("unroll")                                             \
                for (int kh_ = 0; kh_ < 2; ++kh_) {                           \
                    const bf16x8 pa_ = *(const bf16x8*)&pw_[l15 * 72 + kh_ * 32 + quad * 8]; \
                    O[b_][qh_][0] = __builtin_amdgcn_mfma_f32_16x16x32_bf16(  \
                        pa_, vf_[b_][kh_ * 2 + 0], O[b_][qh_][0], 0, 0, 0);   \
                    O[b_][qh_][1] = __builtin_amdgcn_mfma_f32_16x16x32_bf16(  \
                        pa_, vf_[b_][kh_ * 2 + 1], O[b_][qh_][1], 0, 0, 0);   \
                }                                                             \
            }                                                                 \
        }                                                                     \
    } while (0)

    // 9 iterations of 64 keys per wave; mask prefetched one iteration ahead.
    PREFM(A, 0);
    for (int p = 0; p < 4; ++p) {
        COMP(A, 2 * p,     PREFM(B, 2 * p + 1));
        COMP(B, 2 * p + 1, PREFM(A, 2 * p + 2));
    }
    COMP(A, 8, (void)0);

#undef PREFM
#undef COMP

    // ---- reduce row-sum across quads (lanes l15, l15+16, l15+32, l15+48) ----
    #pragma unroll
    for (int b = 0; b < 2; ++b)
        #pragma unroll
        for (int qh = 0; qh < 2; ++qh) {
            lrow[b][qh] += __shfl_xor(lrow[b][qh], 16);
            lrow[b][qh] += __shfl_xor(lrow[b][qh], 32);
        }

    // ---- lifetime switch: everyone done with P-scratch before obuf overlay ----
    __syncthreads();

    float* obuf = (float*)smem;                    // [b][wave][32][32]
    float* lbuf = (float*)(smem + 32768);          // [b][wave][32]

    // ---- write wave partials (row = q = qh*16+quad*4+r, col = d) ----
    #pragma unroll
    for (int b = 0; b < 2; ++b)
        #pragma unroll
        for (int qh = 0; qh < 2; ++qh)
            #pragma unroll
            for (int r = 0; r < 4; ++r) {
                const int row = qh * 16 + quad * 4 + r;
                obuf[(((size_t)b * 4 + wave) * 32 + row) * 32 + l15]      = O[b][qh][0][r];
                obuf[(((size_t)b * 4 + wave) * 32 + row) * 32 + 16 + l15] = O[b][qh][1][r];
            }
    if (lane < 16) {
        #pragma unroll
        for (int b = 0; b < 2; ++b)
            #pragma unroll
            for (int qh = 0; qh < 2; ++qh)
                lbuf[((size_t)b * 4 + wave) * 32 + qh * 16 + l15] = lrow[b][qh];
    }
    __syncthreads();

    // ---- merge 4 wave partials, normalize, write fp32 [b][l][c] ----
    #pragma unroll
    for (int idx = tid; idx < 2048; idx += 256) {
        const int bsel = idx >> 10, row = (idx >> 5) & 31, col = idx & 31;
        float o = 0.f, lsum = 0.f;
        #pragma unroll
        for (int w = 0; w < 4; ++w) {
            o    += obuf[(((size_t)bsel * 4 + w) * 32 + row) * 32 + col];
            lsum += lbuf[((size_t)bsel * 4 + w) * 32 + row];
        }
        attn_out[((size_t)bsel * L + q0 + row) * C + n * HD + col] = o / lsum;
    }
}

// ---------------------------------------------------------------------------
// K4: MFMA GEMM out = (attn_out + lepe) @ wo + bo.
//     Tile 64x64, grid 72 x 4. R11: B staged from prepped wo^T bf16.
// ---------------------------------------------------------------------------
__global__ __launch_bounds__(256) void gemm_out(
    const float* __restrict__ attn_out, const float* __restrict__ lepe,
    const unsigned short* __restrict__ wt_bf, const float* __restrict__ bo,
    float* __restrict__ out)
{
    __shared__ __align__(16) unsigned short As[64 * LSTR];   // 5120 B
    __shared__ __align__(16) unsigned short Bs[64 * LSTR];   // 5120 B

    const int tid  = threadIdx.x;
    const int wave = tid >> 6, lane = tid & 63;
    const int quad = lane >> 4, l15 = lane & 15;
    const int mb = blockIdx.x % 72, nb = blockIdx.x / 72;
    const int row0 = mb * 64, n0 = nb * 64;
    const int mw = (wave & 1) * 32, nw = (wave >> 1) * 32;
    const unsigned short* wt = wt_bf + (size_t)3 * 65536;    // wo^T

    f32x4 acc[2][2];
    #pragma unroll
    for (int t = 0; t < 2; ++t)
        #pragma unroll
        for (int u = 0; u < 2; ++u) acc[t][u] = (f32x4){0,0,0,0};

    for (int kc = 0; kc < 8; ++kc) {
        const int k0 = kc * 32;
        __syncthreads();
        // ---- stage A: 64x32 of (attn_out + lepe). thread: row=tid>>2, q=tid&3
        {
            const int row = tid >> 2, qt = tid & 3;
            const size_t base = (size_t)(row0 + row) * C + k0 + qt * 8;
            #pragma unroll
            for (int j = 0; j < 2; ++j) {
                const f32x4 a = *(const f32x4*)(attn_out + base + j * 4);
                const f32x4 e = *(const f32x4*)(lepe + base + j * 4);
                u16x4 p = { f2b(a[0] + e[0]), f2b(a[1] + e[1]),
                            f2b(a[2] + e[2]), f2b(a[3] + e[3]) };
                *(u16x4*)&As[row * LSTR + qt * 8 + j * 4] = p;
            }
        }
        // ---- stage B: 64x32 bf16 copy from wt[n][k]. thread: n=tid>>2, kq=tid&3
        {
            const int n = tid >> 2, kq = tid & 3;
            const unsigned short* src = wt + (size_t)(n0 + n) * 256 + k0 + kq * 8;
            *(bf16x8*)&Bs[n * LSTR + kq * 8] = *(const bf16x8*)src;
        }
        __syncthreads();
        // ---- MFMA: wave quadrant 32x32 ----
        #pragma unroll
        for (int t = 0; t < 2; ++t) {
            const bf16x8 af = *(const bf16x8*)&As[(mw + t * 16 + l15) * LSTR + quad * 8];
            #pragma unroll
            for (int u = 0; u < 2; ++u) {
                const bf16x8 bfr = *(const bf16x8*)&Bs[(nw + u * 16 + l15) * LSTR + quad * 8];
                acc[t][u] = __builtin_amdgcn_mfma_f32_16x16x32_bf16(af, bfr, acc[t][u], 0, 0, 0);
            }
        }
    }

    // ---- epilogue: + bias, fp32 store ----
    #pragma unroll
    for (int u = 0; u < 2; ++u) {
        const int col = n0 + nw + u * 16 + l15;
        const float bv_ = bo[col];
        #pragma unroll
        for (int t = 0; t < 2; ++t)
            #pragma unroll
            for (int r = 0; r < 4; ++r) {
                const int R = row0 + mw + t * 16 + quad * 4 + r;
                out[(size_t)R * C + col] = acc[t][u][r] + bv_;
            }
    }
}

// ---------------------------------------------------------------------------
extern "C" void kernel_launch(void* const* d_in, const int* in_sizes, int n_in,
                              void* d_out, int out_size, void* d_ws, size_t ws_size,
                              hipStream_t stream)
{
    const float* x    = (const float*)d_in[0];
    const float* sinp = (const float*)d_in[1];
    const float* cosp = (const float*)d_in[2];
    const float* mask = (const float*)d_in[3];
    const float* wq   = (const float*)d_in[4];
    const float* bq   = (const float*)d_in[5];
    const float* wk   = (const float*)d_in[6];
    const float* bk   = (const float*)d_in[7];
    const float* wv   = (const float*)d_in[8];
    const float* bv   = (const float*)d_in[9];
    const float* w_dw = (const float*)d_in[10];
    const float* b_dw = (const float*)d_in[11];
    const float* wo   = (const float*)d_in[12];
    const float* bo   = (const float*)d_in[13];
    float* out = (float*)d_out;

    float* ws = (float*)d_ws;
    const size_t nqkv = (size_t)Bb * NH * L * HD;   // 1179648
    float* v_perm   = ws;                            // nqkv fp32
    float* lepe     = v_perm + nqkv;                 // NROW*C fp32
    float* attn_out = lepe + (size_t)NROW * C;       // NROW*C fp32
    unsigned short* q_bf  = (unsigned short*)(attn_out + (size_t)NROW * C);
    unsigned short* k_bf  = q_bf + nqkv;
    unsigned short* vt_bf = k_bf + nqkv;
    unsigned short* x_bf  = vt_bf + nqkv;            // NROW*C bf16
    unsigned short* wt_bf = x_bf + (size_t)NROW * C; // 4*256*256 bf16

    prep<<<1152 + 256, 256, 0, stream>>>(x, wq, wk, wv, wo, x_bf, wt_bf);
    gemm_qkv<<<36 * 12, 256, 0, stream>>>(x_bf, wt_bf, bq, bk, bv,
                                          sinp, cosp, q_bf, k_bf, v_perm);
    v_transpose<<<Bb * NH * (L / 32), 256, 0, stream>>>(v_perm, vt_bf);
    dwconv<<<(Bb * L * C) / 256, 256, 0, stream>>>(v_perm, w_dw, b_dw, lepe);
    attn_mfma<<<(L / 32) * NH, 256, 0, stream>>>(q_bf, k_bf, vt_bf, mask, attn_out);
    gemm_out<<<72 * 4, 256, 0, stream>>>(attn_out, lepe, wt_bf, bo, out);
}